// Round 1
// baseline (194.826 us; speedup 1.0000x reference)
//
#include <hip/hip_runtime.h>
#include <hip/hip_bf16.h>

// Problem constants (from reference): D=16, N=512, M_HID=5, BATCH=1024
#define D_  16
#define N_  512
#define MH  5
#define B_  1024

// Packed per-(n,d) param block layout (floats):
//  [0..4]   t0  = softplus10(w0)        (5)
//  [5..9]   b0                          (5)
//  [10..14] ta0 = tanh(a0)              (5)
//  [15..39] t1  = softplus10(w1) [k*5+l](25)
//  [40..44] b1                          (5)
//  [45..49] ta1 = tanh(a1)              (5)
//  [50..74] t2  = softplus10(w2)        (25)
//  [75..79] b2                          (5)
//  [80..84] ta2 = tanh(a2)              (5)
//  [85..89] t3  = softplus10(w3)        (5)
//  [90]     b3                          (1)
//  [91..95] pad (zero)
#define PSTRIDE 96
#define PBLK    (D_ * PSTRIDE)   // 1536 floats per n

__device__ __forceinline__ float ftanh(float x) {
    // tanh(x) = 1 - 2/(1+exp(2x)); saturates correctly at +-1, NaN-free for finite x
    float e = __expf(2.0f * x);
    return 1.0f - __fdividef(2.0f, 1.0f + e);
}

__device__ __forceinline__ float sp10(float x) {
    // (1/10)*log(1+exp(10x)), overflow-safe
    float t = 10.0f * x;
    return (t > 20.0f) ? x : 0.1f * __logf(1.0f + __expf(t));
}

__device__ __forceinline__ float sp1(float x) {
    return (x > 20.0f) ? x : __logf(1.0f + __expf(x));
}

// ---------------- Kernel A: parameter preprocessing ----------------
// One thread per (n,d); idx = n*16 + d; output P[idx*96 ...] contiguous.
__global__ __launch_bounds__(256) void prep_kernel(
    const float* __restrict__ w0, const float* __restrict__ b0, const float* __restrict__ a0,
    const float* __restrict__ w1, const float* __restrict__ b1, const float* __restrict__ a1,
    const float* __restrict__ w2, const float* __restrict__ b2, const float* __restrict__ a2,
    const float* __restrict__ w3, const float* __restrict__ b3,
    float* __restrict__ P)
{
    int idx = blockIdx.x * blockDim.x + threadIdx.x;   // n*16 + d
    if (idx >= D_ * N_) return;
    int n = idx >> 4;
    int d = idx & 15;
    int dn = d * N_ + n;   // inputs are [D][N][...]
    float* o = P + idx * PSTRIDE;

    const float* p;
    p = w0 + dn * MH;
    #pragma unroll
    for (int l = 0; l < MH; l++) o[l] = sp10(p[l]);
    p = b0 + dn * MH;
    #pragma unroll
    for (int l = 0; l < MH; l++) o[5 + l] = p[l];
    p = a0 + dn * MH;
    #pragma unroll
    for (int l = 0; l < MH; l++) o[10 + l] = ftanh(p[l]);

    p = w1 + dn * (MH * MH);
    #pragma unroll
    for (int i = 0; i < MH * MH; i++) o[15 + i] = sp10(p[i]);
    p = b1 + dn * MH;
    #pragma unroll
    for (int l = 0; l < MH; l++) o[40 + l] = p[l];
    p = a1 + dn * MH;
    #pragma unroll
    for (int l = 0; l < MH; l++) o[45 + l] = ftanh(p[l]);

    p = w2 + dn * (MH * MH);
    #pragma unroll
    for (int i = 0; i < MH * MH; i++) o[50 + i] = sp10(p[i]);
    p = b2 + dn * MH;
    #pragma unroll
    for (int l = 0; l < MH; l++) o[75 + l] = p[l];
    p = a2 + dn * MH;
    #pragma unroll
    for (int l = 0; l < MH; l++) o[80 + l] = ftanh(p[l]);

    p = w3 + dn * MH;
    #pragma unroll
    for (int l = 0; l < MH; l++) o[85 + l] = sp10(p[l]);
    o[90] = b3[dn];
    #pragma unroll
    for (int i = 91; i < PSTRIDE; i++) o[i] = 0.0f;
}

// ---------------- Kernel B: main evaluation ----------------
// grid = 2048 blocks: blockIdx.x = n*4 + m_chunk. Block handles one n and 256 m's.
// Writes S[n*B_ + m] = sum_d log(phidot + 1e-10).
__global__ __launch_bounds__(256) void eval_kernel(
    const float* __restrict__ X, const float* __restrict__ P, float* __restrict__ S)
{
    __shared__ float q[PBLK];
    const int n  = blockIdx.x >> 2;
    const int mc = blockIdx.x & 3;
    const int tid = threadIdx.x;

    // Stage this n's packed params (6 KB) into LDS, coalesced.
    const float* Pn = P + n * PBLK;
    #pragma unroll
    for (int f = tid; f < PBLK; f += 256) q[f] = Pn[f];

    const int m = mc * 256 + tid;
    // Load this thread's X row (16 floats, 64B aligned) into registers.
    float x[D_];
    const float4* xr = (const float4*)(X + m * D_);
    #pragma unroll
    for (int i = 0; i < 4; i++) {
        float4 v = xr[i];
        x[4*i+0] = v.x; x[4*i+1] = v.y; x[4*i+2] = v.z; x[4*i+3] = v.w;
    }
    __syncthreads();

    float acc = 0.0f;
    for (int d = 0; d < D_; d++) {
        const float* w = q + d * PSTRIDE;   // broadcast reads (same addr all lanes)
        const float xv = x[d];
        float phi[MH], pdot[MH];

        // layer 0 (input width 1, phidot_in = 1)
        #pragma unroll
        for (int l = 0; l < MH; l++) {
            float t  = w[l];
            float z  = fmaf(xv, t, w[5 + l]);
            float tz = ftanh(z);
            float ta = w[10 + l];
            float gate = fmaf(ta, fmaf(-tz, tz, 1.0f), 1.0f);  // 1 + ta*(1 - tz^2)
            pdot[l] = t * gate;
            phi[l]  = fmaf(tz, ta, z);
        }

        // layers 1 and 2 (5x5)
        #pragma unroll
        for (int layer = 0; layer < 2; layer++) {
            const int wb = 15 + layer * 35;   // weights at wb, b at wb+25, ta at wb+30
            float zn[MH], pn[MH];
            #pragma unroll
            for (int l = 0; l < MH; l++) {
                float z   = w[wb + 25 + l];
                float pdn = 0.0f;
                #pragma unroll
                for (int k = 0; k < MH; k++) {
                    float ww = w[wb + k * MH + l];
                    z   = fmaf(phi[k],  ww, z);
                    pdn = fmaf(pdot[k], ww, pdn);
                }
                float tz = ftanh(z);
                float ta = w[wb + 30 + l];
                float gate = fmaf(ta, fmaf(-tz, tz, 1.0f), 1.0f);
                pn[l] = pdn * gate;
                zn[l] = fmaf(tz, ta, z);
            }
            #pragma unroll
            for (int l = 0; l < MH; l++) { phi[l] = zn[l]; pdot[l] = pn[l]; }
        }

        // layer 3 (5 -> 1), sigmoid derivative
        float z = w[90], pdn = 0.0f;
        #pragma unroll
        for (int k = 0; k < MH; k++) {
            float ww = w[85 + k];
            z   = fmaf(phi[k],  ww, z);
            pdn = fmaf(pdot[k], ww, pdn);
        }
        float e = __expf(-z);
        float s = __fdividef(1.0f, 1.0f + e);
        float p = pdn * s * (1.0f - s);
        acc += __logf(p + 1e-10f);
    }
    S[n * B_ + m] = acc;   // coalesced in m
}

// ---------------- Kernel C: per-m logsumexp over n ----------------
// out[m] = log( (sum_n am_n * exp(S[m,n]-M)) / (sum_n am_n) + 1e-10 ) + M
__global__ __launch_bounds__(256) void reduce_kernel(
    const float* __restrict__ S, const float* __restrict__ amix, float* __restrict__ out)
{
    const int m = blockIdx.x;
    const int t = threadIdx.x;

    float sa = S[t * B_ + m];
    float sb = S[(t + 256) * B_ + m];
    float mx = fmaxf(sa, sb);
    #pragma unroll
    for (int o = 32; o; o >>= 1) mx = fmaxf(mx, __shfl_xor(mx, o));

    __shared__ float rmax[4], rs1[4], rs2[4];
    if ((t & 63) == 0) rmax[t >> 6] = mx;
    __syncthreads();
    const float M = fmaxf(fmaxf(rmax[0], rmax[1]), fmaxf(rmax[2], rmax[3]));

    float wa = sp1(amix[t]);
    float wb = sp1(amix[t + 256]);
    float psum = wa + wb;
    float pexp = fmaf(wa, __expf(sa - M), wb * __expf(sb - M));
    #pragma unroll
    for (int o = 32; o; o >>= 1) {
        psum += __shfl_xor(psum, o);
        pexp += __shfl_xor(pexp, o);
    }
    if ((t & 63) == 0) { rs1[t >> 6] = psum; rs2[t >> 6] = pexp; }
    __syncthreads();
    if (t == 0) {
        float s1 = rs1[0] + rs1[1] + rs1[2] + rs1[3];
        float s2 = rs2[0] + rs2[1] + rs2[2] + rs2[3];
        float f  = __fdividef(s2, s1);
        out[m] = __logf(f + 1e-10f) + M;
    }
}

extern "C" void kernel_launch(void* const* d_in, const int* in_sizes, int n_in,
                              void* d_out, int out_size, void* d_ws, size_t ws_size,
                              hipStream_t stream) {
    const float* X    = (const float*)d_in[0];
    const float* w0   = (const float*)d_in[1];
    const float* b0   = (const float*)d_in[2];
    const float* a0   = (const float*)d_in[3];
    const float* w1   = (const float*)d_in[4];
    const float* b1   = (const float*)d_in[5];
    const float* a1   = (const float*)d_in[6];
    const float* w2   = (const float*)d_in[7];
    const float* b2   = (const float*)d_in[8];
    const float* a2   = (const float*)d_in[9];
    const float* w3   = (const float*)d_in[10];
    const float* b3   = (const float*)d_in[11];
    const float* amix = (const float*)d_in[12];
    float* out = (float*)d_out;

    float* P = (float*)d_ws;                       // 8192*96*4   = 3,145,728 B
    float* S = P + (size_t)D_ * N_ * PSTRIDE;      // 512*1024*4  = 2,097,152 B

    prep_kernel<<<(D_ * N_ + 255) / 256, 256, 0, stream>>>(w0, b0, a0, w1, b1, a1,
                                                           w2, b2, a2, w3, b3, P);
    eval_kernel<<<N_ * 4, 256, 0, stream>>>(X, P, S);
    reduce_kernel<<<B_, 256, 0, stream>>>(S, amix, out);
}

// Round 2
// 132.141 us; speedup vs baseline: 1.4744x; 1.4744x over previous
//
#include <hip/hip_runtime.h>
#include <hip/hip_bf16.h>

// Problem constants: D=16, N=512, M_HID=5, BATCH=1024
#define D_  16
#define N_  512
#define MH  5
#define B_  1024

// Table: K_=255 intervals, 256 knots per (d,n) over x in [-6,6].
// x_j = -6 + j*(12/255);  eval: xi = x*21.25 + 127.5 (255/12 = 21.25 exact)
#define KP  256

// Packed per-(n,d) param block layout (floats), dn = n*16+d:
//  [0..4] t0=sp10(w0)  [5..9] b0   [10..14] tanh(a0)
//  [15..39] t1=sp10(w1)[40..44] b1 [45..49] tanh(a1)
//  [50..74] t2=sp10(w2)[75..79] b2 [80..84] tanh(a2)
//  [85..89] t3=sp10(w3)[90] b3     [91..95] pad
#define PSTRIDE 96

__device__ __forceinline__ float ftanh(float x) {
    float e = __expf(2.0f * x);
    return 1.0f - __fdividef(2.0f, 1.0f + e);
}
__device__ __forceinline__ float sp10(float x) {
    float t = 10.0f * x;
    return (t > 20.0f) ? x : 0.1f * __logf(1.0f + __expf(t));
}
__device__ __forceinline__ float sp1(float x) {
    return (x > 20.0f) ? x : __logf(1.0f + __expf(x));
}

// ---------------- Kernel A: parameter preprocessing ----------------
__global__ __launch_bounds__(256) void prep_kernel(
    const float* __restrict__ w0, const float* __restrict__ b0, const float* __restrict__ a0,
    const float* __restrict__ w1, const float* __restrict__ b1, const float* __restrict__ a1,
    const float* __restrict__ w2, const float* __restrict__ b2, const float* __restrict__ a2,
    const float* __restrict__ w3, const float* __restrict__ b3,
    float* __restrict__ P)
{
    int idx = blockIdx.x * blockDim.x + threadIdx.x;   // dn = n*16 + d
    if (idx >= D_ * N_) return;
    int n = idx >> 4;
    int d = idx & 15;
    int dn = d * N_ + n;   // inputs are [D][N][...]
    float* o = P + idx * PSTRIDE;

    const float* p;
    p = w0 + dn * MH;
    #pragma unroll
    for (int l = 0; l < MH; l++) o[l] = sp10(p[l]);
    p = b0 + dn * MH;
    #pragma unroll
    for (int l = 0; l < MH; l++) o[5 + l] = p[l];
    p = a0 + dn * MH;
    #pragma unroll
    for (int l = 0; l < MH; l++) o[10 + l] = ftanh(p[l]);

    p = w1 + dn * (MH * MH);
    #pragma unroll
    for (int i = 0; i < MH * MH; i++) o[15 + i] = sp10(p[i]);
    p = b1 + dn * MH;
    #pragma unroll
    for (int l = 0; l < MH; l++) o[40 + l] = p[l];
    p = a1 + dn * MH;
    #pragma unroll
    for (int l = 0; l < MH; l++) o[45 + l] = ftanh(p[l]);

    p = w2 + dn * (MH * MH);
    #pragma unroll
    for (int i = 0; i < MH * MH; i++) o[50 + i] = sp10(p[i]);
    p = b2 + dn * MH;
    #pragma unroll
    for (int l = 0; l < MH; l++) o[75 + l] = p[l];
    p = a2 + dn * MH;
    #pragma unroll
    for (int l = 0; l < MH; l++) o[80 + l] = ftanh(p[l]);

    p = w3 + dn * MH;
    #pragma unroll
    for (int l = 0; l < MH; l++) o[85 + l] = sp10(p[l]);
    o[90] = b3[dn];
    #pragma unroll
    for (int i = 91; i < PSTRIDE; i++) o[i] = 0.0f;
}

// ---------------- Kernel B: build f_{d,n}(x_j) table ----------------
// One block per dn (8192 blocks), thread j computes knot j.
// T[dn*256 + j] = log(phidot_{d,n}(x_j) + 1e-10)
__global__ __launch_bounds__(256) void table_kernel(
    const float* __restrict__ P, float* __restrict__ T)
{
    __shared__ float w[PSTRIDE];
    const int dn = blockIdx.x;
    const int t  = threadIdx.x;
    if (t < PSTRIDE) w[t] = P[dn * PSTRIDE + t];
    __syncthreads();

    const float xv = fmaf((float)t, 12.0f / 255.0f, -6.0f);
    float phi[MH], pdot[MH];

    // layer 0 (input width 1, phidot_in = 1)
    #pragma unroll
    for (int l = 0; l < MH; l++) {
        float tw = w[l];
        float z  = fmaf(xv, tw, w[5 + l]);
        float tz = ftanh(z);
        float ta = w[10 + l];
        float gate = fmaf(ta, fmaf(-tz, tz, 1.0f), 1.0f);
        pdot[l] = tw * gate;
        phi[l]  = fmaf(tz, ta, z);
    }

    // layers 1 and 2 (5x5)
    #pragma unroll
    for (int layer = 0; layer < 2; layer++) {
        const int wb = 15 + layer * 35;
        float zn[MH], pn[MH];
        #pragma unroll
        for (int l = 0; l < MH; l++) {
            float z   = w[wb + 25 + l];
            float pdn = 0.0f;
            #pragma unroll
            for (int k = 0; k < MH; k++) {
                float ww = w[wb + k * MH + l];
                z   = fmaf(phi[k],  ww, z);
                pdn = fmaf(pdot[k], ww, pdn);
            }
            float tz = ftanh(z);
            float ta = w[wb + 30 + l];
            float gate = fmaf(ta, fmaf(-tz, tz, 1.0f), 1.0f);
            pn[l] = pdn * gate;
            zn[l] = fmaf(tz, ta, z);
        }
        #pragma unroll
        for (int l = 0; l < MH; l++) { phi[l] = zn[l]; pdot[l] = pn[l]; }
    }

    // layer 3 (5 -> 1), sigmoid derivative
    float z = w[90], pdn = 0.0f;
    #pragma unroll
    for (int k = 0; k < MH; k++) {
        float ww = w[85 + k];
        z   = fmaf(phi[k],  ww, z);
        pdn = fmaf(pdot[k], ww, pdn);
    }
    float e = __expf(-z);
    float s = __fdividef(1.0f, 1.0f + e);
    float p = pdn * s * (1.0f - s);
    T[((size_t)dn << 8) + t] = __logf(p + 1e-10f);
}

// ---------------- Kernel C: table-lookup evaluation ----------------
// blockIdx = n*4 + mc; block stages the 16KB table for n, each thread
// does 16 lerps (one per d) and writes S[m][n].
__global__ __launch_bounds__(256) void eval_kernel(
    const float* __restrict__ X, const float* __restrict__ T, float* __restrict__ S)
{
    __shared__ float q[D_ * KP];   // 16 KB
    const int n   = blockIdx.x >> 2;
    const int mc  = blockIdx.x & 3;
    const int tid = threadIdx.x;

    const float4* src = (const float4*)(T + ((size_t)n << 12));
    float4* dst = (float4*)q;
    #pragma unroll
    for (int i = 0; i < 4; i++) dst[tid + 256 * i] = src[tid + 256 * i];

    const int m = mc * 256 + tid;
    float x[D_];
    const float4* xr = (const float4*)(X + m * D_);
    #pragma unroll
    for (int i = 0; i < 4; i++) {
        float4 v = xr[i];
        x[4*i+0] = v.x; x[4*i+1] = v.y; x[4*i+2] = v.z; x[4*i+3] = v.w;
    }
    __syncthreads();

    float acc = 0.0f;
    #pragma unroll
    for (int d = 0; d < D_; d++) {
        float xi = fmaf(x[d], 21.25f, 127.5f);      // (x+6) * 255/12
        xi = fminf(fmaxf(xi, 0.0f), 254.99f);
        int j = (int)xi;
        float fr = xi - (float)j;
        const float* row = q + (d << 8) + j;
        float f0 = row[0];
        float f1 = row[1];
        acc += fmaf(fr, f1 - f0, f0);
    }
    S[(size_t)m * N_ + n] = acc;   // [m][n] layout -> coalesced reduce
}

// ---------------- Kernel D: per-m weighted logsumexp over n ----------------
__global__ __launch_bounds__(256) void reduce_kernel(
    const float* __restrict__ S, const float* __restrict__ amix, float* __restrict__ out)
{
    const int m = blockIdx.x;
    const int t = threadIdx.x;
    const float* row = S + (size_t)m * N_;

    float sa = row[t];
    float sb = row[t + 256];
    float mx = fmaxf(sa, sb);
    #pragma unroll
    for (int o = 32; o; o >>= 1) mx = fmaxf(mx, __shfl_xor(mx, o));

    __shared__ float rmax[4], rs1[4], rs2[4];
    if ((t & 63) == 0) rmax[t >> 6] = mx;
    __syncthreads();
    const float M = fmaxf(fmaxf(rmax[0], rmax[1]), fmaxf(rmax[2], rmax[3]));

    float wa = sp1(amix[t]);
    float wb = sp1(amix[t + 256]);
    float psum = wa + wb;
    float pexp = fmaf(wa, __expf(sa - M), wb * __expf(sb - M));
    #pragma unroll
    for (int o = 32; o; o >>= 1) {
        psum += __shfl_xor(psum, o);
        pexp += __shfl_xor(pexp, o);
    }
    if ((t & 63) == 0) { rs1[t >> 6] = psum; rs2[t >> 6] = pexp; }
    __syncthreads();
    if (t == 0) {
        float s1 = rs1[0] + rs1[1] + rs1[2] + rs1[3];
        float s2 = rs2[0] + rs2[1] + rs2[2] + rs2[3];
        float f  = __fdividef(s2, s1);
        out[m] = __logf(f + 1e-10f) + M;
    }
}

extern "C" void kernel_launch(void* const* d_in, const int* in_sizes, int n_in,
                              void* d_out, int out_size, void* d_ws, size_t ws_size,
                              hipStream_t stream) {
    const float* X    = (const float*)d_in[0];
    const float* w0   = (const float*)d_in[1];
    const float* b0   = (const float*)d_in[2];
    const float* a0   = (const float*)d_in[3];
    const float* w1   = (const float*)d_in[4];
    const float* b1   = (const float*)d_in[5];
    const float* a1   = (const float*)d_in[6];
    const float* w2   = (const float*)d_in[7];
    const float* b2   = (const float*)d_in[8];
    const float* a2   = (const float*)d_in[9];
    const float* w3   = (const float*)d_in[10];
    const float* b3   = (const float*)d_in[11];
    const float* amix = (const float*)d_in[12];
    float* out = (float*)d_out;

    float* P = (float*)d_ws;                               // 8192*96*4  = 3.15 MB
    float* T = P + (size_t)D_ * N_ * PSTRIDE;              // 8192*256*4 = 8.39 MB
    float* S = T + (size_t)D_ * N_ * KP;                   // 1024*512*4 = 2.10 MB

    prep_kernel<<<(D_ * N_ + 255) / 256, 256, 0, stream>>>(w0, b0, a0, w1, b1, a1,
                                                           w2, b2, a2, w3, b3, P);
    table_kernel<<<D_ * N_, 256, 0, stream>>>(P, T);
    eval_kernel<<<N_ * 4, 256, 0, stream>>>(X, T, S);
    reduce_kernel<<<B_, 256, 0, stream>>>(S, amix, out);
}

// Round 3
// 107.302 us; speedup vs baseline: 1.8157x; 1.2315x over previous
//
#include <hip/hip_runtime.h>
#include <hip/hip_bf16.h>

// Problem constants: D=16, N=512, M_HID=5, BATCH=1024
#define D_  16
#define N_  512
#define MH  5
#define B_  1024

// Table: 128 knots per (d,n) over x in [-6,6]; h = 12/127.
#define KP   128
#define KPM1 127

// Packed per-(d,n) param block layout (floats):
//  [0..4] t0=sp10(w0)  [5..9] b0   [10..14] tanh(a0)
//  [15..39] t1=sp10(w1)[40..44] b1 [45..49] tanh(a1)
//  [50..74] t2=sp10(w2)[75..79] b2 [80..84] tanh(a2)
//  [85..89] t3=sp10(w3)[90] b3
#define PSTRIDE 96

__device__ __forceinline__ float ftanh(float x) {
    float e = __expf(2.0f * x);
    return 1.0f - __fdividef(2.0f, 1.0f + e);
}
__device__ __forceinline__ float sp10(float x) {
    float t = 10.0f * x;
    return (t > 20.0f) ? x : 0.1f * __logf(1.0f + __expf(t));
}
__device__ __forceinline__ float sp1(float x) {
    return (x > 20.0f) ? x : __logf(1.0f + __expf(x));
}

// ---------------- Kernel A: fused prep + table build ----------------
// One block per (n,d): blockIdx.x = n*16 + d. Threads 0..90 transform one
// param slot each into LDS; then thread j computes knot j of
// f_{d,n}(x_j) = log(phidot_{d,n}(x_j) + 1e-10).  T[n][d][KP] layout.
__global__ __launch_bounds__(KP) void table_kernel(
    const float* __restrict__ w0, const float* __restrict__ b0, const float* __restrict__ a0,
    const float* __restrict__ w1, const float* __restrict__ b1, const float* __restrict__ a1,
    const float* __restrict__ w2, const float* __restrict__ b2, const float* __restrict__ a2,
    const float* __restrict__ w3, const float* __restrict__ b3,
    float* __restrict__ T)
{
    __shared__ float w[PSTRIDE];
    const int blk = blockIdx.x;      // n*16 + d
    const int n = blk >> 4;
    const int d = blk & 15;
    const int dn = d * N_ + n;       // source tensors are [D][N][...]
    const int t = threadIdx.x;

    if (t < 91) {
        float v;
        if      (t <  5) v = sp10 (w0[dn *  5 + t      ]);
        else if (t < 10) v =       b0[dn *  5 + t -  5 ];
        else if (t < 15) v = ftanh(a0[dn *  5 + t - 10 ]);
        else if (t < 40) v = sp10 (w1[dn * 25 + t - 15 ]);
        else if (t < 45) v =       b1[dn *  5 + t - 40 ];
        else if (t < 50) v = ftanh(a1[dn *  5 + t - 45 ]);
        else if (t < 75) v = sp10 (w2[dn * 25 + t - 50 ]);
        else if (t < 80) v =       b2[dn *  5 + t - 75 ];
        else if (t < 85) v = ftanh(a2[dn *  5 + t - 80 ]);
        else if (t < 90) v = sp10 (w3[dn *  5 + t - 85 ]);
        else             v =       b3[dn];
        w[t] = v;
    }
    __syncthreads();

    const float xv = fmaf((float)t, 12.0f / (float)KPM1, -6.0f);
    float phi[MH], pdot[MH];

    // layer 0 (input width 1, phidot_in = 1)
    #pragma unroll
    for (int l = 0; l < MH; l++) {
        float tw = w[l];
        float z  = fmaf(xv, tw, w[5 + l]);
        float tz = ftanh(z);
        float ta = w[10 + l];
        float gate = fmaf(ta, fmaf(-tz, tz, 1.0f), 1.0f);
        pdot[l] = tw * gate;
        phi[l]  = fmaf(tz, ta, z);
    }

    // layers 1 and 2 (5x5)
    #pragma unroll
    for (int layer = 0; layer < 2; layer++) {
        const int wb = 15 + layer * 35;
        float zn[MH], pn[MH];
        #pragma unroll
        for (int l = 0; l < MH; l++) {
            float z   = w[wb + 25 + l];
            float pdn = 0.0f;
            #pragma unroll
            for (int k = 0; k < MH; k++) {
                float ww = w[wb + k * MH + l];
                z   = fmaf(phi[k],  ww, z);
                pdn = fmaf(pdot[k], ww, pdn);
            }
            float tz = ftanh(z);
            float ta = w[wb + 30 + l];
            float gate = fmaf(ta, fmaf(-tz, tz, 1.0f), 1.0f);
            pn[l] = pdn * gate;
            zn[l] = fmaf(tz, ta, z);
        }
        #pragma unroll
        for (int l = 0; l < MH; l++) { phi[l] = zn[l]; pdot[l] = pn[l]; }
    }

    // layer 3 (5 -> 1), sigmoid derivative
    float z = w[90], pdn = 0.0f;
    #pragma unroll
    for (int k = 0; k < MH; k++) {
        float ww = w[85 + k];
        z   = fmaf(phi[k],  ww, z);
        pdn = fmaf(pdot[k], ww, pdn);
    }
    float e = __expf(-z);
    float s = __fdividef(1.0f, 1.0f + e);
    float p = pdn * s * (1.0f - s);
    T[((size_t)blk << 7) + t] = __logf(p + 1e-10f);
}

// ---------------- Kernel B: table-lookup evaluation ----------------
// blockIdx = n*4 + mc; block stages the 8KB table for n, each thread
// does 16 lerps (one per d) and writes S[m][n].
__global__ __launch_bounds__(256) void eval_kernel(
    const float* __restrict__ X, const float* __restrict__ T, float* __restrict__ S)
{
    __shared__ float q[D_ * KP];   // 8 KB
    const int n   = blockIdx.x >> 2;
    const int mc  = blockIdx.x & 3;
    const int tid = threadIdx.x;

    const float4* src = (const float4*)(T + ((size_t)n << 11));
    float4* dst = (float4*)q;
    #pragma unroll
    for (int i = 0; i < 2; i++) dst[tid + 256 * i] = src[tid + 256 * i];

    const int m = mc * 256 + tid;
    float x[D_];
    const float4* xr = (const float4*)(X + m * D_);
    #pragma unroll
    for (int i = 0; i < 4; i++) {
        float4 v = xr[i];
        x[4*i+0] = v.x; x[4*i+1] = v.y; x[4*i+2] = v.z; x[4*i+3] = v.w;
    }
    __syncthreads();

    float acc = 0.0f;
    #pragma unroll
    for (int d = 0; d < D_; d++) {
        float xi = fmaf(x[d], (float)KPM1 / 12.0f, (float)KPM1 * 0.5f);
        xi = fminf(fmaxf(xi, 0.0f), (float)KPM1 - 0.01f);
        int j = (int)xi;
        float fr = xi - (float)j;
        const float* row = q + (d << 7) + j;
        float f0 = row[0];
        float f1 = row[1];
        acc += fmaf(fr, f1 - f0, f0);
    }
    S[(size_t)m * N_ + n] = acc;   // [m][n] layout -> coalesced reduce
}

// ---------------- Kernel C: per-m weighted logsumexp over n ----------------
__global__ __launch_bounds__(256) void reduce_kernel(
    const float* __restrict__ S, const float* __restrict__ amix, float* __restrict__ out)
{
    const int m = blockIdx.x;
    const int t = threadIdx.x;
    const float* row = S + (size_t)m * N_;

    float sa = row[t];
    float sb = row[t + 256];
    float mx = fmaxf(sa, sb);
    #pragma unroll
    for (int o = 32; o; o >>= 1) mx = fmaxf(mx, __shfl_xor(mx, o));

    __shared__ float rmax[4], rs1[4], rs2[4];
    if ((t & 63) == 0) rmax[t >> 6] = mx;
    __syncthreads();
    const float M = fmaxf(fmaxf(rmax[0], rmax[1]), fmaxf(rmax[2], rmax[3]));

    float wa = sp1(amix[t]);
    float wb = sp1(amix[t + 256]);
    float psum = wa + wb;
    float pexp = fmaf(wa, __expf(sa - M), wb * __expf(sb - M));
    #pragma unroll
    for (int o = 32; o; o >>= 1) {
        psum += __shfl_xor(psum, o);
        pexp += __shfl_xor(pexp, o);
    }
    if ((t & 63) == 0) { rs1[t >> 6] = psum; rs2[t >> 6] = pexp; }
    __syncthreads();
    if (t == 0) {
        float s1 = rs1[0] + rs1[1] + rs1[2] + rs1[3];
        float s2 = rs2[0] + rs2[1] + rs2[2] + rs2[3];
        float f  = __fdividef(s2, s1);
        out[m] = __logf(f + 1e-10f) + M;
    }
}

extern "C" void kernel_launch(void* const* d_in, const int* in_sizes, int n_in,
                              void* d_out, int out_size, void* d_ws, size_t ws_size,
                              hipStream_t stream) {
    const float* X    = (const float*)d_in[0];
    const float* w0   = (const float*)d_in[1];
    const float* b0   = (const float*)d_in[2];
    const float* a0   = (const float*)d_in[3];
    const float* w1   = (const float*)d_in[4];
    const float* b1   = (const float*)d_in[5];
    const float* a1   = (const float*)d_in[6];
    const float* w2   = (const float*)d_in[7];
    const float* b2   = (const float*)d_in[8];
    const float* a2   = (const float*)d_in[9];
    const float* w3   = (const float*)d_in[10];
    const float* b3   = (const float*)d_in[11];
    const float* amix = (const float*)d_in[12];
    float* out = (float*)d_out;

    float* T = (float*)d_ws;                   // 8192*128*4 = 4.19 MB
    float* S = T + (size_t)D_ * N_ * KP;       // 1024*512*4 = 2.10 MB

    table_kernel<<<D_ * N_, KP, 0, stream>>>(w0, b0, a0, w1, b1, a1,
                                             w2, b2, a2, w3, b3, T);
    eval_kernel<<<N_ * 4, 256, 0, stream>>>(X, T, S);
    reduce_kernel<<<B_, 256, 0, stream>>>(S, amix, out);
}

// Round 4
// 101.291 us; speedup vs baseline: 1.9234x; 1.0593x over previous
//
#include <hip/hip_runtime.h>
#include <hip/hip_bf16.h>

// Problem constants: D=16, N=512, M_HID=5, BATCH=1024
#define D_  16
#define N_  512
#define MH  5
#define B_  1024

// Table: 64 knots per (d,n) over x in [-5,5]; h = 10/63.
#define KP   64
#define KPM1 63
#define XMIN -5.0f
#define XSCALE (63.0f / 10.0f)   /* knots per x-unit */

// Packed per-(d,n) param slot layout (floats):
//  [0..4] t0=sp10(w0)  [5..9] b0   [10..14] tanh(a0)
//  [15..39] t1=sp10(w1)[40..44] b1 [45..49] tanh(a1)
//  [50..74] t2=sp10(w2)[75..79] b2 [80..84] tanh(a2)
//  [85..89] t3=sp10(w3)[90] b3
#define PSTRIDE 96
#define DN_PER_BLK 4

__device__ __forceinline__ float ftanh(float x) {
    float e = __expf(2.0f * x);
    return 1.0f - __fdividef(2.0f, 1.0f + e);
}
__device__ __forceinline__ float sp10(float x) {
    float t = 10.0f * x;
    return (t > 20.0f) ? x : 0.1f * __logf(1.0f + __expf(t));
}
__device__ __forceinline__ float sp1(float x) {
    return (x > 20.0f) ? x : __logf(1.0f + __expf(x));
}

// ---------------- Kernel A: fused prep + table build ----------------
// 2048 blocks x 256 threads; each block handles 4 (n,d) slots.
// Thread t: slot group g=t>>6 (wave-uniform), knot j=t&63.
// T[dn][64] layout, dn = n*16+d; writes fully coalesced.
__global__ __launch_bounds__(256) void table_kernel(
    const float* __restrict__ w0, const float* __restrict__ b0, const float* __restrict__ a0,
    const float* __restrict__ w1, const float* __restrict__ b1, const float* __restrict__ a1,
    const float* __restrict__ w2, const float* __restrict__ b2, const float* __restrict__ a2,
    const float* __restrict__ w3, const float* __restrict__ b3,
    float* __restrict__ T)
{
    __shared__ float w[DN_PER_BLK][PSTRIDE];
    const int t = threadIdx.x;

    // Load+transform params for the block's 4 dn slots.
    for (int i = t; i < DN_PER_BLK * 91; i += 256) {
        int local = i / 91;
        int s     = i - local * 91;
        int dng   = blockIdx.x * DN_PER_BLK + local;   // n*16 + d
        int n = dng >> 4;
        int d = dng & 15;
        int dn = d * N_ + n;                            // source tensors are [D][N][...]
        float v;
        if      (s <  5) v = sp10 (w0[dn *  5 + s      ]);
        else if (s < 10) v =       b0[dn *  5 + s -  5 ];
        else if (s < 15) v = ftanh(a0[dn *  5 + s - 10 ]);
        else if (s < 40) v = sp10 (w1[dn * 25 + s - 15 ]);
        else if (s < 45) v =       b1[dn *  5 + s - 40 ];
        else if (s < 50) v = ftanh(a1[dn *  5 + s - 45 ]);
        else if (s < 75) v = sp10 (w2[dn * 25 + s - 50 ]);
        else if (s < 80) v =       b2[dn *  5 + s - 75 ];
        else if (s < 85) v = ftanh(a2[dn *  5 + s - 80 ]);
        else if (s < 90) v = sp10 (w3[dn *  5 + s - 85 ]);
        else             v =       b3[dn];
        w[local][s] = v;
    }
    __syncthreads();

    const int g = t >> 6;          // wave-uniform -> LDS broadcast reads
    const int j = t & 63;
    const float* wp = w[g];
    const float xv = fmaf((float)j, 10.0f / (float)KPM1, XMIN);

    float phi[MH], pdot[MH];

    // layer 0 (input width 1, phidot_in = 1)
    #pragma unroll
    for (int l = 0; l < MH; l++) {
        float tw = wp[l];
        float z  = fmaf(xv, tw, wp[5 + l]);
        float tz = ftanh(z);
        float ta = wp[10 + l];
        float gate = fmaf(ta, fmaf(-tz, tz, 1.0f), 1.0f);
        pdot[l] = tw * gate;
        phi[l]  = fmaf(tz, ta, z);
    }

    // layers 1 and 2 (5x5)
    #pragma unroll
    for (int layer = 0; layer < 2; layer++) {
        const int wb = 15 + layer * 35;
        float zn[MH], pn[MH];
        #pragma unroll
        for (int l = 0; l < MH; l++) {
            float z   = wp[wb + 25 + l];
            float pdn = 0.0f;
            #pragma unroll
            for (int k = 0; k < MH; k++) {
                float ww = wp[wb + k * MH + l];
                z   = fmaf(phi[k],  ww, z);
                pdn = fmaf(pdot[k], ww, pdn);
            }
            float tz = ftanh(z);
            float ta = wp[wb + 30 + l];
            float gate = fmaf(ta, fmaf(-tz, tz, 1.0f), 1.0f);
            pn[l] = pdn * gate;
            zn[l] = fmaf(tz, ta, z);
        }
        #pragma unroll
        for (int l = 0; l < MH; l++) { phi[l] = zn[l]; pdot[l] = pn[l]; }
    }

    // layer 3 (5 -> 1), sigmoid derivative
    float z = wp[90], pdn = 0.0f;
    #pragma unroll
    for (int k = 0; k < MH; k++) {
        float ww = wp[85 + k];
        z   = fmaf(phi[k],  ww, z);
        pdn = fmaf(pdot[k], ww, pdn);
    }
    float e = __expf(-z);
    float s = __fdividef(1.0f, 1.0f + e);
    float p = pdn * s * (1.0f - s);
    T[(size_t)blockIdx.x * 256 + t] = __logf(p + 1e-10f);
}

// ---------------- Kernel B: table-lookup evaluation ----------------
// blockIdx = n*4 + mc; block stages the 4KB table for n, each thread
// does 16 lerps (one per d) and writes S[m][n].
__global__ __launch_bounds__(256) void eval_kernel(
    const float* __restrict__ X, const float* __restrict__ T, float* __restrict__ S)
{
    __shared__ float q[D_ * KP];   // 4 KB
    const int n   = blockIdx.x >> 2;
    const int mc  = blockIdx.x & 3;
    const int tid = threadIdx.x;

    ((float4*)q)[tid] = ((const float4*)(T + ((size_t)n << 10)))[tid];

    const int m = mc * 256 + tid;
    float x[D_];
    const float4* xr = (const float4*)(X + m * D_);
    #pragma unroll
    for (int i = 0; i < 4; i++) {
        float4 v = xr[i];
        x[4*i+0] = v.x; x[4*i+1] = v.y; x[4*i+2] = v.z; x[4*i+3] = v.w;
    }
    __syncthreads();

    float acc = 0.0f;
    #pragma unroll
    for (int d = 0; d < D_; d++) {
        float xi = fmaf(x[d], XSCALE, -XMIN * XSCALE);
        xi = fminf(fmaxf(xi, 0.0f), (float)KPM1 - 0.01f);
        int j = (int)xi;
        float fr = xi - (float)j;
        const float* row = q + (d << 6) + j;
        float f0 = row[0];
        float f1 = row[1];
        acc += fmaf(fr, f1 - f0, f0);
    }
    S[(size_t)m * N_ + n] = acc;   // [m][n] layout -> coalesced reduce
}

// ---------------- Kernel C: per-m weighted logsumexp over n ----------------
__global__ __launch_bounds__(256) void reduce_kernel(
    const float* __restrict__ S, const float* __restrict__ amix, float* __restrict__ out)
{
    const int m = blockIdx.x;
    const int t = threadIdx.x;
    const float* row = S + (size_t)m * N_;

    float sa = row[t];
    float sb = row[t + 256];
    float mx = fmaxf(sa, sb);
    #pragma unroll
    for (int o = 32; o; o >>= 1) mx = fmaxf(mx, __shfl_xor(mx, o));

    __shared__ float rmax[4], rs1[4], rs2[4];
    if ((t & 63) == 0) rmax[t >> 6] = mx;
    __syncthreads();
    const float M = fmaxf(fmaxf(rmax[0], rmax[1]), fmaxf(rmax[2], rmax[3]));

    float wa = sp1(amix[t]);
    float wb = sp1(amix[t + 256]);
    float psum = wa + wb;
    float pexp = fmaf(wa, __expf(sa - M), wb * __expf(sb - M));
    #pragma unroll
    for (int o = 32; o; o >>= 1) {
        psum += __shfl_xor(psum, o);
        pexp += __shfl_xor(pexp, o);
    }
    if ((t & 63) == 0) { rs1[t >> 6] = psum; rs2[t >> 6] = pexp; }
    __syncthreads();
    if (t == 0) {
        float s1 = rs1[0] + rs1[1] + rs1[2] + rs1[3];
        float s2 = rs2[0] + rs2[1] + rs2[2] + rs2[3];
        float f  = __fdividef(s2, s1);
        out[m] = __logf(f + 1e-10f) + M;
    }
}

extern "C" void kernel_launch(void* const* d_in, const int* in_sizes, int n_in,
                              void* d_out, int out_size, void* d_ws, size_t ws_size,
                              hipStream_t stream) {
    const float* X    = (const float*)d_in[0];
    const float* w0   = (const float*)d_in[1];
    const float* b0   = (const float*)d_in[2];
    const float* a0   = (const float*)d_in[3];
    const float* w1   = (const float*)d_in[4];
    const float* b1   = (const float*)d_in[5];
    const float* a1   = (const float*)d_in[6];
    const float* w2   = (const float*)d_in[7];
    const float* b2   = (const float*)d_in[8];
    const float* a2   = (const float*)d_in[9];
    const float* w3   = (const float*)d_in[10];
    const float* b3   = (const float*)d_in[11];
    const float* amix = (const float*)d_in[12];
    float* out = (float*)d_out;

    float* T = (float*)d_ws;                   // 8192*64*4  = 2.10 MB
    float* S = T + (size_t)D_ * N_ * KP;       // 1024*512*4 = 2.10 MB

    table_kernel<<<(D_ * N_) / DN_PER_BLK, 256, 0, stream>>>(
        w0, b0, a0, w1, b1, a1, w2, b2, a2, w3, b3, T);
    eval_kernel<<<N_ * 4, 256, 0, stream>>>(X, T, S);
    reduce_kernel<<<B_, 256, 0, stream>>>(S, amix, out);
}